// Round 15
// baseline (273.828 us; speedup 1.0000x reference)
//
#include <hip/hip_runtime.h>

#define NP 4096
#define DIM 384
#define ML 65536

typedef int i32x4 __attribute__((ext_vector_type(4)));
typedef unsigned short u16;
typedef unsigned long long u64;

#define QSCALE 21.16666667f     // 127/6
#define B2SCALE 224.0138889f    // (127/6)^2 / 2  -- key = b2*s^2/2 - dot_int, monotone in d^2
#define KBIAS (1 << 23)

typedef __attribute__((address_space(1))) unsigned int as1_u32;
typedef __attribute__((address_space(3))) unsigned int as3_u32;

__device__ __forceinline__ void gl_lds16(const void* g, void* l) {
  __builtin_amdgcn_global_load_lds((const as1_u32*)g, (as3_u32*)l, 16, 0, 0);
}

// ---------------- prep: fp32 -> i8 (scale 127/6, clamp) + lib row b2i ----------------
__global__ __launch_bounds__(256) void prep_kernel(const float* __restrict__ patch,
                                                   const float* __restrict__ lib,
                                                   char* __restrict__ Ai8,
                                                   char* __restrict__ Bi8,
                                                   int* __restrict__ b2i) {
  const int row = blockIdx.x * 4 + (threadIdx.x >> 6);
  const int lane = threadIdx.x & 63;
  const float* src;
  char* dst;
  int r;
  if (row < NP) { src = patch; dst = Ai8; r = row; }
  else          { src = lib;   dst = Bi8; r = row - NP; }
  float s = 0.f;
#pragma unroll
  for (int j = 0; j < 3; ++j) {
    const float2 v = *reinterpret_cast<const float2*>(src + (size_t)r * DIM + j * 128 + lane * 2);
    s += v.x * v.x + v.y * v.y;
    const int q0 = __float2int_rn(fminf(fmaxf(v.x, -6.f), 6.f) * QSCALE);
    const int q1 = __float2int_rn(fminf(fmaxf(v.y, -6.f), 6.f) * QSCALE);
    const u16 p = (u16)((q0 & 0xFF) | ((q1 & 0xFF) << 8));
    *reinterpret_cast<u16*>(dst + (size_t)r * DIM + j * 128 + lane * 2) = p;
  }
#pragma unroll
  for (int m = 1; m < 64; m <<= 1) s += __shfl_xor(s, m);
  if (lane == 0 && row >= NP) b2i[r] = __float2int_rn(s * B2SCALE);
}

// ---- fused i8 GEMM + row-min: persistent-A (96 KB, staged once), B dbuf 2x32 KB,
// ---- 256 blocks (1/CU), 16 m-tiles per block, continuous counted-vmcnt stream,
// ---- integer min-key epilogue with direct global atomicMin (no LDS combine).
__global__ __launch_bounds__(512, 2) void gemm_min_kernel(const char* __restrict__ Ai8,
                                                          const char* __restrict__ Bi8,
                                                          const int* __restrict__ b2i,
                                                          u64* __restrict__ packed) {
  __shared__ __align__(16) char As[3][32768];  // 96 KB: kt-planes of A (256 rows x 128 k)
  __shared__ __align__(16) char Bs[2][32768];  // 64 KB dbuf
  const int tid = threadIdx.x;
  const int lane = tid & 63;
  const int w = tid >> 6;          // 0..7
  const int wm = w >> 2;           // patch half
  const int wn = w & 3;            // lib quarter
  const int cl = lane & 15, rg = lane >> 4;

  // 256 blocks: xcd = orig&7; local = orig>>3 (0..31); nt = local&15; mg = xcd*2+(local>>4).
  // Each XCD owns 2 m-groups (16 m-tiles each) -> B slice 3 MB, L2-resident.
  const int orig = blockIdx.x;
  const int xcd = orig & 7;
  const int local = orig >> 3;
  const int nt = local & 15;
  const int mg = xcd * 2 + (local >> 4);
  const int n0 = nt * 256;
  const int mbase = mg * 4096;     // 16 m-tiles x 256

  // staging decomposition: P = i*8192 + tid*16 within a 32KB plane
  int lof[4]; const char* gaA[4]; const char* gbB[4];
#pragma unroll
  for (int i = 0; i < 4; ++i) {
    const int P = i * 8192 + tid * 16;
    const int r = P >> 7;                  // row 0..255
    const int L = P ^ ((r & 7) << 4);      // inverse swizzle
    const int c = L & 127;
    lof[i] = P;
    gaA[i] = Ai8 + (size_t)(n0 + r) * DIM + c;     // + kt*128 per plane
    gbB[i] = Bi8 + (size_t)(mbase + r) * DIM + c;  // + mt*98304 + kt*128
  }

  // fragment byte offsets within a 32KB plane/buf
  int offA[2][8], offB[2][4];
#pragma unroll
  for (int g = 0; g < 2; ++g) {
#pragma unroll
    for (int j = 0; j < 8; ++j) {
      const int row = wm * 128 + j * 16 + cl;
      offA[g][j] = row * 128 + ((g * 64 + rg * 16) ^ ((cl & 7) << 4));
    }
#pragma unroll
    for (int i = 0; i < 4; ++i) {
      const int row = wn * 64 + i * 16 + cl;
      offB[g][i] = row * 128 + ((g * 64 + rg * 16) ^ ((cl & 7) << 4));
    }
  }

  i32x4 acc[4][8] = {};
  i32x4 bc[4];

  // prologue: A (12 loads, all 3 planes) then B(mt=0,kt=0) -> buf0
#pragma unroll
  for (int kt = 0; kt < 3; ++kt)
#pragma unroll
    for (int i = 0; i < 4; ++i)
      gl_lds16(gaA[i] + kt * 128, (char*)As[kt] + lof[i]);
#pragma unroll
  for (int i = 0; i < 4; ++i)
    gl_lds16(gbB[i], (char*)Bs[0] + lof[i]);

#define STAGE_B(MT, KT, BUF)                                                        \
  {                                                                                 \
    _Pragma("unroll")                                                               \
    for (int i = 0; i < 4; ++i)                                                     \
      gl_lds16(gbB[i] + (size_t)(MT) * 98304 + (KT) * 128, (char*)Bs[BUF] + lof[i]); \
  }

#define MFMA_STEP(KT, BUF)                                                          \
  {                                                                                 \
    const char* Ab = (const char*)As[KT];                                           \
    const char* Bb = (const char*)Bs[BUF];                                          \
    _Pragma("unroll")                                                               \
    for (int g = 0; g < 2; ++g) {                                                   \
      i32x4 af[8], bg[4];                                                           \
      _Pragma("unroll")                                                             \
      for (int j = 0; j < 8; ++j) af[j] = *reinterpret_cast<const i32x4*>(Ab + offA[g][j]); \
      _Pragma("unroll")                                                             \
      for (int i = 0; i < 4; ++i) bg[i] = *reinterpret_cast<const i32x4*>(Bb + offB[g][i]); \
      _Pragma("unroll")                                                             \
      for (int i = 0; i < 4; ++i)                                                   \
        _Pragma("unroll")                                                           \
        for (int j = 0; j < 8; ++j)                                                 \
          acc[i][j] = __builtin_amdgcn_mfma_i32_16x16x64_i8(bg[i], af[j], acc[i][j], 0, 0, 0); \
    }                                                                               \
  }

#define EPILOGUE(M0V)                                                               \
  {                                                                                 \
    const int colb = (M0V) + wn * 64 + rg * 4;                                      \
    _Pragma("unroll")                                                               \
    for (int j = 0; j < 8; ++j) {                                                   \
      const int prow = wm * 128 + j * 16 + cl;                                      \
      u64 best = ~0ull;                                                             \
      _Pragma("unroll")                                                             \
      for (int i = 0; i < 4; ++i)                                                   \
        _Pragma("unroll")                                                           \
        for (int r = 0; r < 4; ++r) {                                               \
          const unsigned kb = (unsigned)(bc[i][r] - acc[i][j][r] + KBIAS);          \
          const u64 p = ((u64)kb << 32) | (unsigned)(colb + i * 16 + r);            \
          best = p < best ? p : best;                                               \
        }                                                                           \
      const u64 o1 = __shfl_xor(best, 16); best = o1 < best ? o1 : best;            \
      const u64 o2 = __shfl_xor(best, 32); best = o2 < best ? o2 : best;            \
      if (rg == 0) atomicMin(&packed[n0 + prow], best);                             \
    }                                                                               \
    _Pragma("unroll")                                                               \
    for (int i = 0; i < 4; ++i)                                                     \
      _Pragma("unroll")                                                             \
      for (int j = 0; j < 8; ++j) acc[i][j] = i32x4{0, 0, 0, 0};                    \
  }

#define WAITV(N) asm volatile("s_waitcnt vmcnt(" #N ")" ::: "memory")
#define BARRIER() { __builtin_amdgcn_s_barrier(); __builtin_amdgcn_sched_barrier(0); }

  // per-tile body; BUF0 = parity of (mt*3), i.e. buffer holding (mt,kt=0)
#define TILE_BODY(MT, BUF0, FIRST, LAST)                                            \
  {                                                                                 \
    const int m0v = mbase + (MT) * 256;                                             \
    if (!(FIRST)) { EPILOGUE(m0v - 256); }                                          \
    STAGE_B(MT, 1, (BUF0) ^ 1);                                                     \
    _Pragma("unroll")                                                               \
    for (int i = 0; i < 4; ++i)                                                     \
      bc[i] = *reinterpret_cast<const i32x4*>(&b2i[m0v + wn * 64 + rg * 4 + i * 16]); \
    if (FIRST) { WAITV(8); } else { WAITV(16); }                                    \
    BARRIER();                                                                      \
    MFMA_STEP(0, (BUF0));                                                           \
    BARRIER();                                                                      \
    STAGE_B(MT, 2, (BUF0));                                                         \
    WAITV(8);                                                                       \
    BARRIER();                                                                      \
    MFMA_STEP(1, (BUF0) ^ 1);                                                       \
    BARRIER();                                                                      \
    if (!(LAST)) { STAGE_B((MT) + 1, 0, (BUF0) ^ 1); WAITV(4); }                    \
    else         { WAITV(0); }                                                      \
    BARRIER();                                                                      \
    MFMA_STEP(2, (BUF0));                                                           \
    BARRIER();                                                                      \
  }

  // 16 m-tiles; buffer parity of (mt,0) alternates per mt -> unroll by 2
#pragma unroll 1
  for (int mt2 = 0; mt2 < 8; ++mt2) {
    const int mtA = mt2 * 2;
    TILE_BODY(mtA, 0, (mtA == 0), false);
    TILE_BODY(mtA + 1, 1, false, (mtA + 1 == 15));
  }
  EPILOGUE(mbase + 15 * 256);

#undef TILE_BODY
#undef WAITV
#undef BARRIER
#undef EPILOGUE
#undef MFMA_STEP
#undef STAGE_B
}

// ---------------- exact fp32 recompute of min_val at the chosen argmin ----------------
__global__ __launch_bounds__(256) void exactmin_kernel(const float* __restrict__ patch,
                                                       const float* __restrict__ lib,
                                                       u64* __restrict__ packed) {
  const int n = blockIdx.x * 4 + (threadIdx.x >> 6);
  const int lane = threadIdx.x & 63;
  const int idx = (int)(unsigned)packed[n];
  float s = 0.f;
#pragma unroll
  for (int j = 0; j < 3; ++j) {
    const float2 a = *reinterpret_cast<const float2*>(patch + (size_t)n * DIM + j * 128 + lane * 2);
    const float2 b = *reinterpret_cast<const float2*>(lib + (size_t)idx * DIM + j * 128 + lane * 2);
    const float d0 = a.x - b.x, d1 = a.y - b.y;
    s += d0 * d0 + d1 * d1;
  }
#pragma unroll
  for (int m = 1; m < 64; m <<= 1) s += __shfl_xor(s, m);
  if (lane == 0) packed[n] = ((u64)__float_as_uint(fmaxf(s, 0.f)) << 32) | (unsigned)idx;
}

// ---------------- candidate rows near the max ----------------
__global__ __launch_bounds__(256) void cand_kernel(const u64* __restrict__ packed,
                                                   int* __restrict__ cand) {
  const int tid = threadIdx.x;
  float mx = -1.f;
  for (int n = tid; n < NP; n += 256) {
    const float v = __uint_as_float((unsigned)(packed[n] >> 32));
    mx = fmaxf(mx, v);
  }
#pragma unroll
  for (int m = 1; m < 64; m <<= 1) mx = fmaxf(mx, __shfl_xor(mx, m));
  __shared__ float wmax[4];
  __shared__ float smax;
  if ((tid & 63) == 0) wmax[tid >> 6] = mx;
  __syncthreads();
  if (tid == 0) {
    smax = fmaxf(fmaxf(wmax[0], wmax[1]), fmaxf(wmax[2], wmax[3]));
    cand[0] = 0;
  }
  __syncthreads();
  const float thr = smax - 8.0f;  // d^2 margin >> i8 quantization noise + flip gap
  for (int n = tid; n < NP; n += 256) {
    const float v = __uint_as_float((unsigned)(packed[n] >> 32));
    if (v >= thr) {
      const int slot = atomicAdd(&cand[0], 1);
      if (slot < 256) cand[1 + slot] = n;
    }
  }
}

// ---------------- exact fp32 refinement: block owns 32 lib rows ----------------
__global__ __launch_bounds__(256) void refine_kernel(const float* __restrict__ patch,
                                                     const float* __restrict__ lib,
                                                     const int* __restrict__ cand,
                                                     u64* __restrict__ refined) {
  const int cnt = min(cand[0], 256);
  const int tid = threadIdx.x, lane = tid & 63, w = tid >> 6;
  const int base = blockIdx.x * 32;  // 2048 blocks
  __shared__ float a[8][DIM];        // 12 KB candidate staging
  __shared__ u64 rb[8][4];

  for (int g0 = 0; g0 < cnt; g0 += 8) {
    const int gc = min(cnt - g0, 8);
    for (int i = tid; i < gc * DIM; i += 256) {
      const int c = i / DIM, e = i - c * DIM;
      a[c][e] = patch[(size_t)cand[1 + g0 + c] * DIM + e];
    }
    __syncthreads();

    u64 wbest[8];
#pragma unroll
    for (int c = 0; c < 8; ++c) wbest[c] = ~0ull;

    for (int it = 0; it < 8; ++it) {
      const int m = base + w * 8 + it;
      float lr[6];
#pragma unroll
      for (int j = 0; j < 3; ++j) {
        const float2 v = *reinterpret_cast<const float2*>(lib + (size_t)m * DIM + j * 128 + lane * 2);
        lr[j * 2] = v.x; lr[j * 2 + 1] = v.y;
      }
#pragma unroll
      for (int c = 0; c < 8; ++c) {
        if (c >= gc) break;
        float s = 0.f;
#pragma unroll
        for (int j = 0; j < 3; ++j) {
          const float d0 = lr[j * 2] - a[c][j * 128 + lane * 2];
          const float d1 = lr[j * 2 + 1] - a[c][j * 128 + lane * 2 + 1];
          s += d0 * d0 + d1 * d1;
        }
#pragma unroll
        for (int msk = 1; msk < 64; msk <<= 1) s += __shfl_xor(s, msk);
        const u64 p = ((u64)__float_as_uint(s) << 32) | (unsigned)m;
        wbest[c] = p < wbest[c] ? p : wbest[c];
      }
    }
    if (lane == 0) {
#pragma unroll
      for (int c = 0; c < 8; ++c)
        if (c < gc) rb[c][w] = wbest[c];
    }
    __syncthreads();
    if (tid < gc) {
      u64 b = rb[tid][0];
#pragma unroll
      for (int k = 1; k < 4; ++k) b = rb[tid][k] < b ? rb[tid][k] : b;
      atomicMin(&refined[g0 + tid], b);
    }
    __syncthreads();
  }
}

// ---------------- pick exact argmax row ----------------
__global__ __launch_bounds__(256) void pick_kernel(const u64* __restrict__ refined,
                                                   const int* __restrict__ cand,
                                                   int* __restrict__ scal_i,
                                                   float* __restrict__ scal_f) {
  const int tid = threadIdx.x, lane = tid & 63, w = tid >> 6;
  const int cnt = min(cand[0], 256);
  float v = -1.f;
  int nrow = 0x7FFFFFFF;
  int mi = 0;
  if (tid < cnt) {
    const u64 p = refined[tid];
    v = __uint_as_float((unsigned)(p >> 32));
    nrow = cand[1 + tid];
    mi = (int)(unsigned)p;
  }
#pragma unroll
  for (int msk = 1; msk < 64; msk <<= 1) {
    const float ov = __shfl_xor(v, msk);
    const int on = __shfl_xor(nrow, msk);
    const int om = __shfl_xor(mi, msk);
    if (ov > v || (ov == v && on < nrow)) { v = ov; nrow = on; mi = om; }
  }
  __shared__ float sv[4]; __shared__ int sn[4]; __shared__ int sm[4];
  if (lane == 0) { sv[w] = v; sn[w] = nrow; sm[w] = mi; }
  __syncthreads();
  if (tid == 0) {
    for (int k = 1; k < 4; ++k)
      if (sv[k] > v || (sv[k] == v && sn[k] < nrow)) { v = sv[k]; nrow = sn[k]; mi = sm[k]; }
    scal_i[0] = nrow;       // s_idx
    scal_i[1] = mi;         // m_star index
    scal_f[0] = sqrtf(fmaxf(v, 0.f));  // s_star
  }
}

// ---------------- fused w_dist + per-block top-3 (block owns 32 rows) ----------------
__device__ __forceinline__ void ins3u(u64 x, u64* v) {
  if (x < v[2]) {
    v[2] = x;
    if (v[2] < v[1]) { u64 t = v[1]; v[1] = v[2]; v[2] = t; }
    if (v[1] < v[0]) { u64 t = v[0]; v[0] = v[1]; v[1] = t; }
  }
}

__global__ __launch_bounds__(256) void wtop_kernel(const float* __restrict__ lib,
                                                   const int* __restrict__ scal_i,
                                                   u64* __restrict__ t3) {
  __shared__ float a[DIM];
  __shared__ u64 sv[12];
  const int tid = threadIdx.x, lane = tid & 63, w = tid >> 6;
  const int ms = scal_i[1];
  for (int i = tid; i < DIM; i += 256) a[i] = lib[(size_t)ms * DIM + i];
  __syncthreads();
  const int base = blockIdx.x * 32;  // 2048 blocks
  u64 v[3] = {~0ull, ~0ull, ~0ull};
  for (int it = 0; it < 8; ++it) {
    const int m = base + w * 8 + it;
    float s = 0.f;
#pragma unroll
    for (int j = 0; j < 3; ++j) {
      const float2 lv = *reinterpret_cast<const float2*>(lib + (size_t)m * DIM + j * 128 + lane * 2);
      const float d0 = lv.x - a[j * 128 + lane * 2];
      const float d1 = lv.y - a[j * 128 + lane * 2 + 1];
      s += d0 * d0 + d1 * d1;
    }
#pragma unroll
    for (int msk = 1; msk < 64; msk <<= 1) s += __shfl_xor(s, msk);
    ins3u(((u64)__float_as_uint(s) << 32) | (unsigned)m, v);  // wave-uniform
  }
  if (lane == 0) {
#pragma unroll
    for (int k = 0; k < 3; ++k) sv[w * 3 + k] = v[k];
  }
  __syncthreads();
  if (tid == 0) {
    u64 fv[3] = {~0ull, ~0ull, ~0ull};
    for (int k = 0; k < 12; ++k) ins3u(sv[k], fv);
#pragma unroll
    for (int k = 0; k < 3; ++k) t3[blockIdx.x * 3 + k] = fv[k];
  }
}

// ---------------- stage-2 top-3 + final score ----------------
__global__ __launch_bounds__(256) void final_kernel(const u64* __restrict__ t3,
                                                    const float* __restrict__ patch,
                                                    const float* __restrict__ lib,
                                                    const int* __restrict__ scal_i,
                                                    const float* __restrict__ scal_f,
                                                    float* __restrict__ out) {
  const int tid = threadIdx.x, lane = tid & 63, w = tid >> 6;
  u64 v[3] = {~0ull, ~0ull, ~0ull};
  for (int i = tid; i < 6144; i += 256) ins3u(t3[i], v);
#pragma unroll
  for (int msk = 1; msk < 64; msk <<= 1) {
    u64 o0 = __shfl_xor(v[0], msk);
    u64 o1 = __shfl_xor(v[1], msk);
    u64 o2 = __shfl_xor(v[2], msk);
    ins3u(o0, v); ins3u(o1, v); ins3u(o2, v);
  }
  __shared__ u64 sv[12];
  __shared__ int nn[2]; __shared__ float kk[2];
  if (lane == 0) {
#pragma unroll
    for (int k = 0; k < 3; ++k) sv[w * 3 + k] = v[k];
  }
  __syncthreads();
  if (tid == 0) {
    u64 fv[3] = {~0ull, ~0ull, ~0ull};
    for (int k = 0; k < 12; ++k) ins3u(sv[k], fv);
    nn[0] = (int)(unsigned)fv[1];  // skip fv[0] == m_star itself
    nn[1] = (int)(unsigned)fv[2];
  }
  __syncthreads();
  if (w < 2) {
    const int s_idx = scal_i[0];
    const int nnx = nn[w];
    float s = 0.f;
#pragma unroll
    for (int k = 0; k < 6; ++k) {
      const float d = patch[(size_t)s_idx * DIM + lane + k * 64] - lib[(size_t)nnx * DIM + lane + k * 64];
      s += d * d;
    }
#pragma unroll
    for (int msk = 1; msk < 64; msk <<= 1) s += __shfl_xor(s, msk);
    if (lane == 0) kk[w] = sqrtf(s);
  }
  __syncthreads();
  if (tid == 0) {
    const float s_star = scal_f[0];
    const float Ds = 19.59591794f;  // sqrt(384)
    const float wt = 1.0f - expf(s_star / Ds) / (expf(kk[0] / Ds) + expf(kk[1] / Ds));
    out[0] = wt * s_star;
  }
}

// ---------------- fused score map: resize + blurV + blurH in one kernel ----------------
__device__ __constant__ float BW[9] = {
    0.0816741424f, 0.1016453893f, 0.1188358540f, 0.1305155396f, 0.1346581512f,
    0.1305155396f, 0.1188358540f, 0.1016453893f, 0.0816741424f};

__global__ __launch_bounds__(256) void scoremap_kernel(const u64* __restrict__ packed,
                                                       float* __restrict__ out) {
  // 128 blocks x 4 output rows each
  __shared__ float mv[4096];        // 16 KB
  __shared__ float t1b[12][512];    // 24 KB: t1 rows y0-4 .. y0+7 (zero outside image)
  __shared__ float t2b[4][512];     // 8 KB
  const int tid = threadIdx.x;
  const int y0 = blockIdx.x * 4;

  for (int i = tid; i < 4096; i += 256)
    mv[i] = sqrtf(fmaxf(__uint_as_float((unsigned)(packed[i] >> 32)), 0.f));
  __syncthreads();

  for (int i = tid; i < 12 * 512; i += 256) {
    const int ry = i >> 9, x = i & 511;
    const int y = y0 - 4 + ry;
    float v = 0.f;
    if (y >= 0 && y < 512) {
      const float sy = y * 0.125f - 0.4375f;
      const float sx = x * 0.125f - 0.4375f;
      const int yy = (int)floorf(sy); const float fy = sy - (float)yy;
      const int xx = (int)floorf(sx); const float fx = sx - (float)xx;
      const int ya = max(yy, 0), yb = min(yy + 1, 63);
      const int xa = max(xx, 0), xb = min(xx + 1, 63);
      v = (1.f - fy) * ((1.f - fx) * mv[ya * 64 + xa] + fx * mv[ya * 64 + xb]) +
          fy * ((1.f - fx) * mv[yb * 64 + xa] + fx * mv[yb * 64 + xb]);
    }
    t1b[ry][x] = v;
  }
  __syncthreads();

  for (int i = tid; i < 4 * 512; i += 256) {
    const int r = i >> 9, x = i & 511;
    float s = 0.f;
#pragma unroll
    for (int k = -4; k <= 4; ++k) s += BW[k + 4] * t1b[r + 4 + k][x];
    t2b[r][x] = s;
  }
  __syncthreads();

  for (int i = tid; i < 4 * 512; i += 256) {
    const int r = i >> 9, x = i & 511;
    float s = 0.f;
#pragma unroll
    for (int k = -4; k <= 4; ++k) {
      const int xx = x + k;
      if (xx >= 0 && xx < 512) s += BW[k + 4] * t2b[r][xx];
    }
    out[(y0 + r) * 512 + x] = s;
  }
}

extern "C" void kernel_launch(void* const* d_in, const int* in_sizes, int n_in,
                              void* d_out, int out_size, void* d_ws, size_t ws_size,
                              hipStream_t stream) {
  const float* patch = (const float*)d_in[0];
  const float* lib = (const float*)d_in[1];
  float* out = (float*)d_out;

  char* ws = (char*)d_ws;
  size_t off = 0;
  auto alloc = [&](size_t bytes) {
    void* p = ws + off;
    off += (bytes + 255) & ~(size_t)255;
    return p;
  };
  char* Ai8 = (char*)alloc((size_t)NP * DIM);
  char* Bi8 = (char*)alloc((size_t)ML * DIM);
  int* b2i = (int*)alloc(ML * 4);
  u64* packed = (u64*)alloc(NP * 8);
  u64* refined = (u64*)alloc(256 * 8);
  int* cand = (int*)alloc(257 * 4);
  int* scal_i = (int*)alloc(64);
  float* scal_f = (float*)alloc(64);
  u64* t3 = (u64*)alloc(2048 * 3 * 8);

  hipMemsetAsync(packed, 0xFF, NP * 8, stream);
  hipMemsetAsync(refined, 0xFF, 256 * 8, stream);

  prep_kernel<<<(NP + ML) / 4, 256, 0, stream>>>(patch, lib, Ai8, Bi8, b2i);
  gemm_min_kernel<<<256, 512, 0, stream>>>(Ai8, Bi8, b2i, packed);
  exactmin_kernel<<<NP / 4, 256, 0, stream>>>(patch, lib, packed);
  cand_kernel<<<1, 256, 0, stream>>>(packed, cand);
  refine_kernel<<<2048, 256, 0, stream>>>(patch, lib, cand, refined);
  pick_kernel<<<1, 256, 0, stream>>>(refined, cand, scal_i, scal_f);
  wtop_kernel<<<2048, 256, 0, stream>>>(lib, scal_i, t3);
  final_kernel<<<1, 256, 0, stream>>>(t3, patch, lib, scal_i, scal_f, out);
  scoremap_kernel<<<128, 256, 0, stream>>>(packed, out + 1);
}

// Round 16
// 259.395 us; speedup vs baseline: 1.0556x; 1.0556x over previous
//
#include <hip/hip_runtime.h>

#define NP 4096
#define DIM 384
#define ML 65536

typedef int i32x4 __attribute__((ext_vector_type(4)));
typedef unsigned short u16;
typedef unsigned long long u64;

#define QSCALE 21.16666667f     // 127/6
#define B2SCALE 224.0138889f    // (127/6)^2 / 2  -- key = b2*s^2/2 - dot_int, monotone in d^2
#define KBIAS (1 << 23)

typedef __attribute__((address_space(1))) unsigned int as1_u32;
typedef __attribute__((address_space(3))) unsigned int as3_u32;

__device__ __forceinline__ void gl_lds16(const void* g, void* l) {
  __builtin_amdgcn_global_load_lds((const as1_u32*)g, (as3_u32*)l, 16, 0, 0);
}

// ---------------- prep: fp32 -> i8 (scale 127/6, clamp) + lib row b2i ----------------
__global__ __launch_bounds__(256) void prep_kernel(const float* __restrict__ patch,
                                                   const float* __restrict__ lib,
                                                   char* __restrict__ Ai8,
                                                   char* __restrict__ Bi8,
                                                   int* __restrict__ b2i) {
  const int row = blockIdx.x * 4 + (threadIdx.x >> 6);
  const int lane = threadIdx.x & 63;
  const float* src;
  char* dst;
  int r;
  if (row < NP) { src = patch; dst = Ai8; r = row; }
  else          { src = lib;   dst = Bi8; r = row - NP; }
  float s = 0.f;
#pragma unroll
  for (int j = 0; j < 3; ++j) {
    const float2 v = *reinterpret_cast<const float2*>(src + (size_t)r * DIM + j * 128 + lane * 2);
    s += v.x * v.x + v.y * v.y;
    const int q0 = __float2int_rn(fminf(fmaxf(v.x, -6.f), 6.f) * QSCALE);
    const int q1 = __float2int_rn(fminf(fmaxf(v.y, -6.f), 6.f) * QSCALE);
    const u16 p = (u16)((q0 & 0xFF) | ((q1 & 0xFF) << 8));
    *reinterpret_cast<u16*>(dst + (size_t)r * DIM + j * 128 + lane * 2) = p;
  }
#pragma unroll
  for (int m = 1; m < 64; m <<= 1) s += __shfl_xor(s, m);
  if (lane == 0 && row >= NP) b2i[r] = __float2int_rn(s * B2SCALE);
}

// ---- fused i8 GEMM + row-min: 256x256 tile, 8 waves, BK=128, LDS dbuf,
// ---- integer min-key epilogue, exactmin repairs values downstream.
__global__ __launch_bounds__(512, 2) void gemm_min_kernel(const char* __restrict__ Ai8,
                                                          const char* __restrict__ Bi8,
                                                          const int* __restrict__ b2i,
                                                          u64* __restrict__ packed) {
  __shared__ __align__(16) char As[2][32768];  // 64 KB (256 rows x 128 k i8)
  __shared__ __align__(16) char Bs[2][32768];  // 64 KB
  const int tid = threadIdx.x;
  const int lane = tid & 63;
  const int w = tid >> 6;          // 0..7
  const int wm = w >> 2;           // patch half
  const int wn = w & 3;            // lib quarter
  const int cl = lane & 15, rg = lane >> 4;

  // XCD remap: nwg=4096. xt fastest (16 patch tiles), contiguous yt per XCD.
  const int orig = blockIdx.x;
  const int logical = (orig & 7) * 512 + (orig >> 3);
  const int xt = logical & 15;
  const int yt = logical >> 4;
  const int n0 = xt * 256;   // patch rows
  const int m0 = yt * 256;   // lib rows

  // staging addresses (tile-invariant, advanced by +=128 per tile); 128B rows
  const char* ga[4]; const char* gb[4]; int lof[4];
#pragma unroll
  for (int i = 0; i < 4; ++i) {
    const int P = i * 8192 + tid * 16;     // linear LDS dest byte in 32KB tile
    const int r = P >> 7;                  // tile row (128B per row), 0..255
    const int L = P ^ ((r & 7) << 4);      // inverse-swizzled source offset
    const int c = L & 127;                 // byte col within row
    lof[i] = P;
    ga[i] = Ai8 + (size_t)(n0 + r) * DIM + c;
    gb[i] = Bi8 + (size_t)(m0 + r) * DIM + c;
  }

  // fragment byte offsets (tile-invariant); g = k64-group within BK=128
  int offA[2][8], offB[2][4];
#pragma unroll
  for (int g = 0; g < 2; ++g) {
#pragma unroll
    for (int j = 0; j < 8; ++j) {
      const int row = wm * 128 + j * 16 + cl;
      offA[g][j] = row * 128 + ((g * 64 + rg * 16) ^ ((cl & 7) << 4));
    }
#pragma unroll
    for (int i = 0; i < 4; ++i) {
      const int row = wn * 64 + i * 16 + cl;
      offB[g][i] = row * 128 + ((g * 64 + rg * 16) ^ ((cl & 7) << 4));
    }
  }

  i32x4 acc[4][8] = {};

  // prologue: stage tile 0 into buf 0 (8 loads)
#pragma unroll
  for (int i = 0; i < 4; ++i) { gl_lds16(ga[i], (char*)As[0] + lof[i]); ga[i] += 128; }
#pragma unroll
  for (int i = 0; i < 4; ++i) { gl_lds16(gb[i], (char*)Bs[0] + lof[i]); gb[i] += 128; }

#pragma unroll
  for (int kt = 0; kt < 3; ++kt) {
    const int buf = kt & 1;
    if (kt < 2) {
#pragma unroll
      for (int i = 0; i < 4; ++i) { gl_lds16(ga[i], (char*)As[buf ^ 1] + lof[i]); ga[i] += 128; }
#pragma unroll
      for (int i = 0; i < 4; ++i) { gl_lds16(gb[i], (char*)Bs[buf ^ 1] + lof[i]); gb[i] += 128; }
      asm volatile("s_waitcnt vmcnt(8)" ::: "memory");  // tile kt landed; kt+1 in flight
    } else {
      asm volatile("s_waitcnt vmcnt(0)" ::: "memory");
    }
    __builtin_amdgcn_s_barrier();
    __builtin_amdgcn_sched_barrier(0);

    const char* Ab = (const char*)As[buf];
    const char* Bb = (const char*)Bs[buf];
#pragma unroll
    for (int g = 0; g < 2; ++g) {
      i32x4 af[8], bg[4];
#pragma unroll
      for (int j = 0; j < 8; ++j)
        af[j] = *reinterpret_cast<const i32x4*>(Ab + offA[g][j]);
#pragma unroll
      for (int i = 0; i < 4; ++i)
        bg[i] = *reinterpret_cast<const i32x4*>(Bb + offB[g][i]);
      // swapped operands: D[lib][patch] -> patch row = cl in C/D layout
#pragma unroll
      for (int i = 0; i < 4; ++i)
#pragma unroll
        for (int j = 0; j < 8; ++j)
          acc[i][j] = __builtin_amdgcn_mfma_i32_16x16x64_i8(bg[i], af[j], acc[i][j], 0, 0, 0);
    }
    __builtin_amdgcn_s_barrier();
    __builtin_amdgcn_sched_barrier(0);
  }

  // epilogue: lane (cl,rg), frag (i,j), reg r holds int dot for
  //   patch row = n0 + wm*128 + j*16 + cl ; lib col = m0 + wn*64 + i*16 + rg*4 + r
  // integer ordering key (per row): b2i[col] - dot  (monotone in d^2)
  const int colb = m0 + wn * 64 + rg * 4;
  i32x4 bc[4];
#pragma unroll
  for (int i = 0; i < 4; ++i)
    bc[i] = *reinterpret_cast<const i32x4*>(&b2i[colb + i * 16]);

  u64* sh = reinterpret_cast<u64*>(As);  // 8KB epilogue scratch

#pragma unroll
  for (int j = 0; j < 8; ++j) {
    const int prow = wm * 128 + j * 16 + cl;
    u64 best = ~0ull;
#pragma unroll
    for (int i = 0; i < 4; ++i)
#pragma unroll
      for (int r = 0; r < 4; ++r) {
        const unsigned kb = (unsigned)(bc[i][r] - acc[i][j][r] + KBIAS);
        const u64 p = ((u64)kb << 32) | (unsigned)(colb + i * 16 + r);
        best = p < best ? p : best;
      }
    const u64 o1 = __shfl_xor(best, 16); best = o1 < best ? o1 : best;
    const u64 o2 = __shfl_xor(best, 32); best = o2 < best ? o2 : best;
    if (rg == 0) sh[prow * 4 + wn] = best;
  }
  __syncthreads();
  if (tid < 256) {
    u64 v = sh[tid * 4];
#pragma unroll
    for (int k = 1; k < 4; ++k) { const u64 o = sh[tid * 4 + k]; v = o < v ? o : v; }
    atomicMin(&packed[n0 + tid], v);
  }
}

// ---------------- exact fp32 recompute of min_val at the chosen argmin ----------------
__global__ __launch_bounds__(256) void exactmin_kernel(const float* __restrict__ patch,
                                                       const float* __restrict__ lib,
                                                       u64* __restrict__ packed) {
  const int n = blockIdx.x * 4 + (threadIdx.x >> 6);
  const int lane = threadIdx.x & 63;
  const int idx = (int)(unsigned)packed[n];
  float s = 0.f;
#pragma unroll
  for (int j = 0; j < 3; ++j) {
    const float2 a = *reinterpret_cast<const float2*>(patch + (size_t)n * DIM + j * 128 + lane * 2);
    const float2 b = *reinterpret_cast<const float2*>(lib + (size_t)idx * DIM + j * 128 + lane * 2);
    const float d0 = a.x - b.x, d1 = a.y - b.y;
    s += d0 * d0 + d1 * d1;
  }
#pragma unroll
  for (int m = 1; m < 64; m <<= 1) s += __shfl_xor(s, m);
  if (lane == 0) packed[n] = ((u64)__float_as_uint(fmaxf(s, 0.f)) << 32) | (unsigned)idx;
}

// ---------------- candidate rows near the max ----------------
__global__ __launch_bounds__(256) void cand_kernel(const u64* __restrict__ packed,
                                                   int* __restrict__ cand) {
  const int tid = threadIdx.x;
  float mx = -1.f;
  for (int n = tid; n < NP; n += 256) {
    const float v = __uint_as_float((unsigned)(packed[n] >> 32));
    mx = fmaxf(mx, v);
  }
#pragma unroll
  for (int m = 1; m < 64; m <<= 1) mx = fmaxf(mx, __shfl_xor(mx, m));
  __shared__ float wmax[4];
  __shared__ float smax;
  if ((tid & 63) == 0) wmax[tid >> 6] = mx;
  __syncthreads();
  if (tid == 0) {
    smax = fmaxf(fmaxf(wmax[0], wmax[1]), fmaxf(wmax[2], wmax[3]));
    cand[0] = 0;
  }
  __syncthreads();
  const float thr = smax - 8.0f;  // d^2 margin >> i8 quantization noise + flip gap
  for (int n = tid; n < NP; n += 256) {
    const float v = __uint_as_float((unsigned)(packed[n] >> 32));
    if (v >= thr) {
      const int slot = atomicAdd(&cand[0], 1);
      if (slot < 256) cand[1 + slot] = n;
    }
  }
}

// ---------------- exact fp32 refinement: block owns 32 lib rows ----------------
__global__ __launch_bounds__(256) void refine_kernel(const float* __restrict__ patch,
                                                     const float* __restrict__ lib,
                                                     const int* __restrict__ cand,
                                                     u64* __restrict__ refined) {
  const int cnt = min(cand[0], 256);
  const int tid = threadIdx.x, lane = tid & 63, w = tid >> 6;
  const int base = blockIdx.x * 32;  // 2048 blocks
  __shared__ float a[8][DIM];        // 12 KB candidate staging
  __shared__ u64 rb[8][4];

  for (int g0 = 0; g0 < cnt; g0 += 8) {
    const int gc = min(cnt - g0, 8);
    for (int i = tid; i < gc * DIM; i += 256) {
      const int c = i / DIM, e = i - c * DIM;
      a[c][e] = patch[(size_t)cand[1 + g0 + c] * DIM + e];
    }
    __syncthreads();

    u64 wbest[8];
#pragma unroll
    for (int c = 0; c < 8; ++c) wbest[c] = ~0ull;

    for (int it = 0; it < 8; ++it) {
      const int m = base + w * 8 + it;
      float lr[6];
#pragma unroll
      for (int j = 0; j < 3; ++j) {
        const float2 v = *reinterpret_cast<const float2*>(lib + (size_t)m * DIM + j * 128 + lane * 2);
        lr[j * 2] = v.x; lr[j * 2 + 1] = v.y;
      }
#pragma unroll
      for (int c = 0; c < 8; ++c) {
        if (c >= gc) break;
        float s = 0.f;
#pragma unroll
        for (int j = 0; j < 3; ++j) {
          const float d0 = lr[j * 2] - a[c][j * 128 + lane * 2];
          const float d1 = lr[j * 2 + 1] - a[c][j * 128 + lane * 2 + 1];
          s += d0 * d0 + d1 * d1;
        }
#pragma unroll
        for (int msk = 1; msk < 64; msk <<= 1) s += __shfl_xor(s, msk);
        const u64 p = ((u64)__float_as_uint(s) << 32) | (unsigned)m;
        wbest[c] = p < wbest[c] ? p : wbest[c];
      }
    }
    if (lane == 0) {
#pragma unroll
      for (int c = 0; c < 8; ++c)
        if (c < gc) rb[c][w] = wbest[c];
    }
    __syncthreads();
    if (tid < gc) {
      u64 b = rb[tid][0];
#pragma unroll
      for (int k = 1; k < 4; ++k) b = rb[tid][k] < b ? rb[tid][k] : b;
      atomicMin(&refined[g0 + tid], b);
    }
    __syncthreads();
  }
}

// ---------------- pick exact argmax row ----------------
__global__ __launch_bounds__(256) void pick_kernel(const u64* __restrict__ refined,
                                                   const int* __restrict__ cand,
                                                   int* __restrict__ scal_i,
                                                   float* __restrict__ scal_f) {
  const int tid = threadIdx.x, lane = tid & 63, w = tid >> 6;
  const int cnt = min(cand[0], 256);
  float v = -1.f;
  int nrow = 0x7FFFFFFF;
  int mi = 0;
  if (tid < cnt) {
    const u64 p = refined[tid];
    v = __uint_as_float((unsigned)(p >> 32));
    nrow = cand[1 + tid];
    mi = (int)(unsigned)p;
  }
#pragma unroll
  for (int msk = 1; msk < 64; msk <<= 1) {
    const float ov = __shfl_xor(v, msk);
    const int on = __shfl_xor(nrow, msk);
    const int om = __shfl_xor(mi, msk);
    if (ov > v || (ov == v && on < nrow)) { v = ov; nrow = on; mi = om; }
  }
  __shared__ float sv[4]; __shared__ int sn[4]; __shared__ int sm[4];
  if (lane == 0) { sv[w] = v; sn[w] = nrow; sm[w] = mi; }
  __syncthreads();
  if (tid == 0) {
    for (int k = 1; k < 4; ++k)
      if (sv[k] > v || (sv[k] == v && sn[k] < nrow)) { v = sv[k]; nrow = sn[k]; mi = sm[k]; }
    scal_i[0] = nrow;       // s_idx
    scal_i[1] = mi;         // m_star index
    scal_f[0] = sqrtf(fmaxf(v, 0.f));  // s_star
  }
}

// ---------------- fused w_dist + per-block top-3 (block owns 32 rows) ----------------
__device__ __forceinline__ void ins3u(u64 x, u64* v) {
  if (x < v[2]) {
    v[2] = x;
    if (v[2] < v[1]) { u64 t = v[1]; v[1] = v[2]; v[2] = t; }
    if (v[1] < v[0]) { u64 t = v[0]; v[0] = v[1]; v[1] = t; }
  }
}

__global__ __launch_bounds__(256) void wtop_kernel(const float* __restrict__ lib,
                                                   const int* __restrict__ scal_i,
                                                   u64* __restrict__ t3) {
  __shared__ float a[DIM];
  __shared__ u64 sv[12];
  const int tid = threadIdx.x, lane = tid & 63, w = tid >> 6;
  const int ms = scal_i[1];
  for (int i = tid; i < DIM; i += 256) a[i] = lib[(size_t)ms * DIM + i];
  __syncthreads();
  const int base = blockIdx.x * 32;  // 2048 blocks
  u64 v[3] = {~0ull, ~0ull, ~0ull};
  for (int it = 0; it < 8; ++it) {
    const int m = base + w * 8 + it;
    float s = 0.f;
#pragma unroll
    for (int j = 0; j < 3; ++j) {
      const float2 lv = *reinterpret_cast<const float2*>(lib + (size_t)m * DIM + j * 128 + lane * 2);
      const float d0 = lv.x - a[j * 128 + lane * 2];
      const float d1 = lv.y - a[j * 128 + lane * 2 + 1];
      s += d0 * d0 + d1 * d1;
    }
#pragma unroll
    for (int msk = 1; msk < 64; msk <<= 1) s += __shfl_xor(s, msk);
    ins3u(((u64)__float_as_uint(s) << 32) | (unsigned)m, v);  // wave-uniform
  }
  if (lane == 0) {
#pragma unroll
    for (int k = 0; k < 3; ++k) sv[w * 3 + k] = v[k];
  }
  __syncthreads();
  if (tid == 0) {
    u64 fv[3] = {~0ull, ~0ull, ~0ull};
    for (int k = 0; k < 12; ++k) ins3u(sv[k], fv);
#pragma unroll
    for (int k = 0; k < 3; ++k) t3[blockIdx.x * 3 + k] = fv[k];
  }
}

// ---------------- stage-2 top-3 + final score ----------------
__global__ __launch_bounds__(256) void final_kernel(const u64* __restrict__ t3,
                                                    const float* __restrict__ patch,
                                                    const float* __restrict__ lib,
                                                    const int* __restrict__ scal_i,
                                                    const float* __restrict__ scal_f,
                                                    float* __restrict__ out) {
  const int tid = threadIdx.x, lane = tid & 63, w = tid >> 6;
  u64 v[3] = {~0ull, ~0ull, ~0ull};
  for (int i = tid; i < 6144; i += 256) ins3u(t3[i], v);
#pragma unroll
  for (int msk = 1; msk < 64; msk <<= 1) {
    u64 o0 = __shfl_xor(v[0], msk);
    u64 o1 = __shfl_xor(v[1], msk);
    u64 o2 = __shfl_xor(v[2], msk);
    ins3u(o0, v); ins3u(o1, v); ins3u(o2, v);
  }
  __shared__ u64 sv[12];
  __shared__ int nn[2]; __shared__ float kk[2];
  if (lane == 0) {
#pragma unroll
    for (int k = 0; k < 3; ++k) sv[w * 3 + k] = v[k];
  }
  __syncthreads();
  if (tid == 0) {
    u64 fv[3] = {~0ull, ~0ull, ~0ull};
    for (int k = 0; k < 12; ++k) ins3u(sv[k], fv);
    nn[0] = (int)(unsigned)fv[1];  // skip fv[0] == m_star itself
    nn[1] = (int)(unsigned)fv[2];
  }
  __syncthreads();
  if (w < 2) {
    const int s_idx = scal_i[0];
    const int nnx = nn[w];
    float s = 0.f;
#pragma unroll
    for (int k = 0; k < 6; ++k) {
      const float d = patch[(size_t)s_idx * DIM + lane + k * 64] - lib[(size_t)nnx * DIM + lane + k * 64];
      s += d * d;
    }
#pragma unroll
    for (int msk = 1; msk < 64; msk <<= 1) s += __shfl_xor(s, msk);
    if (lane == 0) kk[w] = sqrtf(s);
  }
  __syncthreads();
  if (tid == 0) {
    const float s_star = scal_f[0];
    const float Ds = 19.59591794f;  // sqrt(384)
    const float wt = 1.0f - expf(s_star / Ds) / (expf(kk[0] / Ds) + expf(kk[1] / Ds));
    out[0] = wt * s_star;
  }
}

// ---------------- fused score map: resize + blurV + blurH in one kernel ----------------
__device__ __constant__ float BW[9] = {
    0.0816741424f, 0.1016453893f, 0.1188358540f, 0.1305155396f, 0.1346581512f,
    0.1305155396f, 0.1188358540f, 0.1016453893f, 0.0816741424f};

__global__ __launch_bounds__(256) void scoremap_kernel(const u64* __restrict__ packed,
                                                       float* __restrict__ out) {
  // 128 blocks x 4 output rows each
  __shared__ float mv[4096];        // 16 KB
  __shared__ float t1b[12][512];    // 24 KB: t1 rows y0-4 .. y0+7 (zero outside image)
  __shared__ float t2b[4][512];     // 8 KB
  const int tid = threadIdx.x;
  const int y0 = blockIdx.x * 4;

  for (int i = tid; i < 4096; i += 256)
    mv[i] = sqrtf(fmaxf(__uint_as_float((unsigned)(packed[i] >> 32)), 0.f));
  __syncthreads();

  for (int i = tid; i < 12 * 512; i += 256) {
    const int ry = i >> 9, x = i & 511;
    const int y = y0 - 4 + ry;
    float v = 0.f;
    if (y >= 0 && y < 512) {
      const float sy = y * 0.125f - 0.4375f;
      const float sx = x * 0.125f - 0.4375f;
      const int yy = (int)floorf(sy); const float fy = sy - (float)yy;
      const int xx = (int)floorf(sx); const float fx = sx - (float)xx;
      const int ya = max(yy, 0), yb = min(yy + 1, 63);
      const int xa = max(xx, 0), xb = min(xx + 1, 63);
      v = (1.f - fy) * ((1.f - fx) * mv[ya * 64 + xa] + fx * mv[ya * 64 + xb]) +
          fy * ((1.f - fx) * mv[yb * 64 + xa] + fx * mv[yb * 64 + xb]);
    }
    t1b[ry][x] = v;
  }
  __syncthreads();

  for (int i = tid; i < 4 * 512; i += 256) {
    const int r = i >> 9, x = i & 511;
    float s = 0.f;
#pragma unroll
    for (int k = -4; k <= 4; ++k) s += BW[k + 4] * t1b[r + 4 + k][x];
    t2b[r][x] = s;
  }
  __syncthreads();

  for (int i = tid; i < 4 * 512; i += 256) {
    const int r = i >> 9, x = i & 511;
    float s = 0.f;
#pragma unroll
    for (int k = -4; k <= 4; ++k) {
      const int xx = x + k;
      if (xx >= 0 && xx < 512) s += BW[k + 4] * t2b[r][xx];
    }
    out[(y0 + r) * 512 + x] = s;
  }
}

extern "C" void kernel_launch(void* const* d_in, const int* in_sizes, int n_in,
                              void* d_out, int out_size, void* d_ws, size_t ws_size,
                              hipStream_t stream) {
  const float* patch = (const float*)d_in[0];
  const float* lib = (const float*)d_in[1];
  float* out = (float*)d_out;

  char* ws = (char*)d_ws;
  size_t off = 0;
  auto alloc = [&](size_t bytes) {
    void* p = ws + off;
    off += (bytes + 255) & ~(size_t)255;
    return p;
  };
  char* Ai8 = (char*)alloc((size_t)NP * DIM);
  char* Bi8 = (char*)alloc((size_t)ML * DIM);
  int* b2i = (int*)alloc(ML * 4);
  u64* packed = (u64*)alloc(NP * 8);
  u64* refined = (u64*)alloc(256 * 8);
  int* cand = (int*)alloc(257 * 4);
  int* scal_i = (int*)alloc(64);
  float* scal_f = (float*)alloc(64);
  u64* t3 = (u64*)alloc(2048 * 3 * 8);

  hipMemsetAsync(packed, 0xFF, NP * 8, stream);
  hipMemsetAsync(refined, 0xFF, 256 * 8, stream);

  prep_kernel<<<(NP + ML) / 4, 256, 0, stream>>>(patch, lib, Ai8, Bi8, b2i);
  gemm_min_kernel<<<4096, 512, 0, stream>>>(Ai8, Bi8, b2i, packed);
  exactmin_kernel<<<NP / 4, 256, 0, stream>>>(patch, lib, packed);
  cand_kernel<<<1, 256, 0, stream>>>(packed, cand);
  refine_kernel<<<2048, 256, 0, stream>>>(patch, lib, cand, refined);
  pick_kernel<<<1, 256, 0, stream>>>(refined, cand, scal_i, scal_f);
  wtop_kernel<<<2048, 256, 0, stream>>>(lib, scal_i, t3);
  final_kernel<<<1, 256, 0, stream>>>(t3, patch, lib, scal_i, scal_f, out);
  scoremap_kernel<<<128, 256, 0, stream>>>(packed, out + 1);
}